// Round 1
// baseline (309.568 us; speedup 1.0000x reference)
//
#include <hip/hip_runtime.h>

// Shapes: B=2, F=T=2048, HIDDEN=1024, HEADS=16, DEPTH=64
#define LDT 72  // padded LDS row length (bf16 elems): 144B rows -> 2-way max bank aliasing (free)

typedef __attribute__((ext_vector_type(8))) short short8v;  // 8 bf16 (4 VGPRs)
typedef __attribute__((ext_vector_type(4))) float f32x4;

#define MFMA(a, b, c) __builtin_amdgcn_mfma_f32_16x16x32_bf16((a), (b), (c), 0, 0, 0)

__device__ __forceinline__ unsigned short f2bf(float f) {  // RNE fp32->bf16
  unsigned int u = __float_as_uint(f);
  u = (u + 0x7fffu + ((u >> 16) & 1u)) >> 16;
  return (unsigned short)u;
}
__device__ __forceinline__ float bf2f(unsigned short h) {
  return __uint_as_float(((unsigned int)h) << 16);
}

// ---------------- fp32 -> bf16 convert (x4 vectorized), optional scale ----------------
__global__ void k_cvt(const float* __restrict__ in, unsigned short* __restrict__ out,
                      int n4, float scale) {
  int stride = gridDim.x * blockDim.x;
  for (int i = blockIdx.x * blockDim.x + threadIdx.x; i < n4; i += stride) {
    float4 v = reinterpret_cast<const float4*>(in)[i];
    ushort4 o;
    o.x = f2bf(v.x * scale); o.y = f2bf(v.y * scale);
    o.z = f2bf(v.z * scale); o.w = f2bf(v.w * scale);
    reinterpret_cast<ushort4*>(out)[i] = o;
  }
}

// ------------- transpose+convert 1024x1024 weight: out[j][i] = in[i][j]*scale -------------
__global__ void k_cvt_t(const float* __restrict__ in, unsigned short* __restrict__ out,
                        float scale) {
  __shared__ float tile[32][33];
  int bx = blockIdx.x * 32, by = blockIdx.y * 32;
  int tx = threadIdx.x, ty = threadIdx.y;  // block (32,8)
  for (int r = ty; r < 32; r += 8)
    tile[r][tx] = in[(size_t)(by + r) * 1024 + bx + tx];
  __syncthreads();
  for (int r = ty; r < 32; r += 8)
    out[(size_t)(bx + r) * 1024 + by + tx] = f2bf(tile[tx][r] * scale);
}

// ---------------- bf16 GEMM: C[4096][1024] = A[4096][1024] * BT[1024][1024]^T ----------------
// mode 0: store bf16 to [b][head][s][64]   (Q, K)
// mode 1: store bf16 to [b][head][64][s]   (V transposed)
// mode 2: store fp32 row-major [4096][1024] (final output)
__global__ __launch_bounds__(256)
void k_gemm(const unsigned short* __restrict__ A, const unsigned short* __restrict__ BT,
            void* __restrict__ dst, int mode) {
  __shared__ __align__(16) unsigned short Al[128 * LDT];
  __shared__ __align__(16) unsigned short Bl[128 * LDT];
  const int tid = threadIdx.x;
  const int lane = tid & 63, wid = tid >> 6;
  const int g = lane >> 4, l15 = lane & 15;
  const int wm = wid >> 1, wn = wid & 1;
  const int rowbase = blockIdx.y * 128;
  const int colbase = blockIdx.x * 128;

  const f32x4 zf = {0.f, 0.f, 0.f, 0.f};
  f32x4 acc[4][4];
  for (int m = 0; m < 4; ++m)
    for (int n = 0; n < 4; ++n) acc[m][n] = zf;

  for (int k0 = 0; k0 < 1024; k0 += 64) {
    for (int idx = tid; idx < 1024; idx += 256) {
      int r = idx >> 3, o8 = (idx & 7) << 3;
      *reinterpret_cast<short8v*>(&Al[r * LDT + o8]) =
          *reinterpret_cast<const short8v*>(&A[(size_t)(rowbase + r) * 1024 + k0 + o8]);
      *reinterpret_cast<short8v*>(&Bl[r * LDT + o8]) =
          *reinterpret_cast<const short8v*>(&BT[(size_t)(colbase + r) * 1024 + k0 + o8]);
    }
    __syncthreads();
    for (int kk = 0; kk < 2; ++kk) {
      short8v af[4], bf[4];
      for (int m = 0; m < 4; ++m)
        af[m] = *reinterpret_cast<const short8v*>(
            &Al[(wm * 64 + m * 16 + l15) * LDT + kk * 32 + g * 8]);
      for (int n = 0; n < 4; ++n)
        bf[n] = *reinterpret_cast<const short8v*>(
            &Bl[(wn * 64 + n * 16 + l15) * LDT + kk * 32 + g * 8]);
      for (int m = 0; m < 4; ++m)
        for (int n = 0; n < 4; ++n) acc[m][n] = MFMA(af[m], bf[n], acc[m][n]);
    }
    __syncthreads();
  }

  for (int m = 0; m < 4; ++m) {
    for (int n = 0; n < 4; ++n) {
      for (int r = 0; r < 4; ++r) {
        int row = rowbase + wm * 64 + m * 16 + g * 4 + r;  // C/D: row=(lane>>4)*4+reg
        int col = colbase + wn * 64 + n * 16 + l15;        //      col=lane&15
        float v = acc[m][n][r];
        if (mode == 2) {
          reinterpret_cast<float*>(dst)[(size_t)row * 1024 + col] = v;
        } else {
          int b = row >> 11, s = row & 2047;
          int hd = col >> 6, h = col & 63;
          unsigned short* o = reinterpret_cast<unsigned short*>(dst);
          if (mode == 0)
            o[((size_t)(b * 16 + hd) * 2048 + s) * 64 + h] = f2bf(v);
          else
            o[((size_t)(b * 16 + hd) * 64 + h) * 2048 + s] = f2bf(v);
        }
      }
    }
  }
}

// ---------------- flash attention: per block = (f-tile of 128, one (b,head)) ----------------
__global__ __launch_bounds__(256)
void k_attn(const unsigned short* __restrict__ qw,    // [B*N][F][64] (already * DEPTH^-0.5)
            const unsigned short* __restrict__ kw,    // [B*N][T][64]
            const unsigned short* __restrict__ vtw,   // [B*N][64][T]
            const unsigned short* __restrict__ biasb, // [F][T] bf16
            unsigned short* __restrict__ attnb) {     // [B][F][N*64] bf16
  __shared__ __align__(16) unsigned short Kl[64 * LDT];
  __shared__ __align__(16) unsigned short Vl[64 * LDT];
  __shared__ __align__(16) unsigned short Pl[4][32 * LDT];

  const int tid = threadIdx.x;
  const int lane = tid & 63, wid = tid >> 6;
  const int g = lane >> 4, l15 = lane & 15;

  const int bid = blockIdx.x;     // bid = ftile*32 + bn  (bias-slab locality)
  const int ft = bid >> 5;
  const int bn = bid & 31;
  const int b = bn >> 4, n = bn & 15;

  const size_t hoff = (size_t)bn * 2048 * 64;
  const unsigned short* qp = qw + hoff;
  const unsigned short* kp = kw + hoff;
  const unsigned short* vp = vtw + hoff;

  const int fw = ft * 128 + wid * 32;  // this wave's 32 f-rows

  short8v aq[2][2];  // Q frags: [rowgroup][k-chunk]
  for (int rg = 0; rg < 2; ++rg)
    for (int kk = 0; kk < 2; ++kk)
      aq[rg][kk] = *reinterpret_cast<const short8v*>(
          &qp[(size_t)(fw + rg * 16 + l15) * 64 + kk * 32 + g * 8]);

  const f32x4 zf = {0.f, 0.f, 0.f, 0.f};
  f32x4 o[2][4];
  float ms[2][4], ls[2][4];
  for (int rg = 0; rg < 2; ++rg) {
    for (int ht = 0; ht < 4; ++ht) o[rg][ht] = zf;
    for (int r = 0; r < 4; ++r) { ms[rg][r] = -1e30f; ls[rg][r] = 0.f; }
  }

  for (int t0 = 0; t0 < 2048; t0 += 64) {
    // stage K chunk [64][64] and V^T chunk [64][64]
    for (int idx = tid; idx < 512; idx += 256) {
      int r = idx >> 3, o8 = (idx & 7) << 3;
      *reinterpret_cast<short8v*>(&Kl[r * LDT + o8]) =
          *reinterpret_cast<const short8v*>(&kp[(size_t)(t0 + r) * 64 + o8]);
      *reinterpret_cast<short8v*>(&Vl[r * LDT + o8]) =
          *reinterpret_cast<const short8v*>(&vp[(size_t)r * 2048 + t0 + o8]);
    }

    // prefetch bias into registers (overlaps staging/MFMA latency)
    float bv[2][4][4];
    for (int rg = 0; rg < 2; ++rg)
      for (int r = 0; r < 4; ++r) {
        size_t brow = (size_t)(fw + rg * 16 + g * 4 + r) * 2048 + t0 + l15;
        for (int tt = 0; tt < 4; ++tt) bv[rg][r][tt] = bf2f(biasb[brow + tt * 16]);
      }

    __syncthreads();

    // S = Q*K^T  (K frags shared across both rowgroups)
    f32x4 s[2][4];
    for (int tt = 0; tt < 4; ++tt) {
      short8v kb0 = *reinterpret_cast<const short8v*>(&Kl[(tt * 16 + l15) * LDT + g * 8]);
      short8v kb1 = *reinterpret_cast<const short8v*>(&Kl[(tt * 16 + l15) * LDT + 32 + g * 8]);
      for (int rg = 0; rg < 2; ++rg) {
        f32x4 tacc = MFMA(aq[rg][0], kb0, zf);
        s[rg][tt] = MFMA(aq[rg][1], kb1, tacc);
      }
    }
    for (int rg = 0; rg < 2; ++rg)
      for (int tt = 0; tt < 4; ++tt)
        for (int r = 0; r < 4; ++r) s[rg][tt][r] += bv[rg][r][tt];

    // online softmax (rows live in 16-lane groups; shfl_xor 1/2/4/8 stays in-group)
    for (int rg = 0; rg < 2; ++rg) {
      float tm[4], sc[4], rs[4];
      for (int r = 0; r < 4; ++r) {
        float v = fmaxf(fmaxf(s[rg][0][r], s[rg][1][r]), fmaxf(s[rg][2][r], s[rg][3][r]));
        tm[r] = v;
      }
      for (int d = 1; d <= 8; d <<= 1)
        for (int r = 0; r < 4; ++r) tm[r] = fmaxf(tm[r], __shfl_xor(tm[r], d));
      for (int r = 0; r < 4; ++r) {
        float mn = fmaxf(ms[rg][r], tm[r]);
        sc[r] = __expf(ms[rg][r] - mn);
        ms[rg][r] = mn;
        rs[r] = 0.f;
      }
      for (int tt = 0; tt < 4; ++tt)
        for (int r = 0; r < 4; ++r) {
          float p = __expf(s[rg][tt][r] - ms[rg][r]);
          s[rg][tt][r] = p;
          rs[r] += p;
        }
      for (int d = 1; d <= 8; d <<= 1)
        for (int r = 0; r < 4; ++r) rs[r] += __shfl_xor(rs[r], d);
      for (int r = 0; r < 4; ++r) ls[rg][r] = ls[rg][r] * sc[r] + rs[r];
      for (int ht = 0; ht < 4; ++ht)
        for (int r = 0; r < 4; ++r) o[rg][ht][r] *= sc[r];
      // P: C/D layout -> LDS (wave-private; compiler inserts lgkmcnt, no barrier needed)
      for (int tt = 0; tt < 4; ++tt)
        for (int r = 0; r < 4; ++r)
          Pl[wid][(rg * 16 + g * 4 + r) * LDT + tt * 16 + l15] = f2bf(s[rg][tt][r]);
    }

    // O += P * V
    for (int c = 0; c < 2; ++c) {
      short8v pa[2];
      for (int rg = 0; rg < 2; ++rg)
        pa[rg] = *reinterpret_cast<const short8v*>(
            &Pl[wid][(rg * 16 + l15) * LDT + c * 32 + g * 8]);
      for (int ht = 0; ht < 4; ++ht) {
        short8v vb = *reinterpret_cast<const short8v*>(
            &Vl[(ht * 16 + l15) * LDT + c * 32 + g * 8]);
        for (int rg = 0; rg < 2; ++rg) o[rg][ht] = MFMA(pa[rg], vb, o[rg][ht]);
      }
    }
    __syncthreads();
  }

  for (int rg = 0; rg < 2; ++rg) {
    float inv[4];
    for (int r = 0; r < 4; ++r) inv[r] = 1.f / ls[rg][r];
    for (int ht = 0; ht < 4; ++ht)
      for (int r = 0; r < 4; ++r) {
        int f = fw + rg * 16 + g * 4 + r;
        attnb[((size_t)b * 2048 + f) * 1024 + n * 64 + ht * 16 + l15] =
            f2bf(o[rg][ht][r] * inv[r]);
      }
  }
}

extern "C" void kernel_launch(void* const* d_in, const int* in_sizes, int n_in,
                              void* d_out, int out_size, void* d_ws, size_t ws_size,
                              hipStream_t stream) {
  const float* query  = (const float*)d_in[0];
  const float* source = (const float*)d_in[1];
  const float* bias   = (const float*)d_in[2];
  const float* wq     = (const float*)d_in[3];
  const float* wk     = (const float*)d_in[4];
  const float* wv     = (const float*)d_in[5];
  const float* wo     = (const float*)d_in[6];

  char* ws = (char*)d_ws;  // 64 MB total
  unsigned short* qin_b  = (unsigned short*)(ws + 0);         // [4096][1024] bf16
  unsigned short* src_b  = (unsigned short*)(ws + 8388608);   // [4096][1024]
  unsigned short* wqT    = (unsigned short*)(ws + 16777216);  // [1024][1024] (x0.125)
  unsigned short* wkT    = (unsigned short*)(ws + 18874368);
  unsigned short* wvT    = (unsigned short*)(ws + 20971520);
  unsigned short* woT    = (unsigned short*)(ws + 23068672);  // [e][nh]
  unsigned short* bias_b = (unsigned short*)(ws + 25165824);  // [2048][2048] bf16
  unsigned short* q_ws   = (unsigned short*)(ws + 33554432);  // [32][2048][64]
  unsigned short* k_ws   = (unsigned short*)(ws + 41943040);  // [32][2048][64]
  unsigned short* vT_ws  = (unsigned short*)(ws + 50331648);  // [32][64][2048]
  unsigned short* attn_b = (unsigned short*)(ws + 58720256);  // [4096][1024]

  k_cvt<<<2048, 256, 0, stream>>>(query,  qin_b,  1048576, 1.0f);
  k_cvt<<<2048, 256, 0, stream>>>(source, src_b,  1048576, 1.0f);
  k_cvt<<<2048, 256, 0, stream>>>(bias,   bias_b, 1048576, 1.0f);
  dim3 tb(32, 8);
  k_cvt_t<<<dim3(32, 32), tb, 0, stream>>>(wq, wqT, 0.125f);  // fold DEPTH^-0.5
  k_cvt_t<<<dim3(32, 32), tb, 0, stream>>>(wk, wkT, 1.0f);
  k_cvt_t<<<dim3(32, 32), tb, 0, stream>>>(wv, wvT, 1.0f);
  k_cvt_t<<<dim3(32, 32), tb, 0, stream>>>(wo, woT, 1.0f);

  k_gemm<<<dim3(8, 32), 256, 0, stream>>>(qin_b, wqT, q_ws, 0);
  k_gemm<<<dim3(8, 32), 256, 0, stream>>>(src_b, wkT, k_ws, 0);
  k_gemm<<<dim3(8, 32), 256, 0, stream>>>(src_b, wvT, vT_ws, 1);
  k_attn<<<512, 256, 0, stream>>>(q_ws, k_ws, vT_ws, bias_b, attn_b);
  k_gemm<<<dim3(8, 32), 256, 0, stream>>>(attn_b, woT, d_out, 2);
}

// Round 2
// 190.141 us; speedup vs baseline: 1.6281x; 1.6281x over previous
//
#include <hip/hip_runtime.h>

// Shapes: B=2, F=T=2048, HIDDEN=1024, HEADS=16, DEPTH=64
#define LDT 72  // padded LDS row (bf16 elems) for attention tiles
#define LOG2E 1.44269504f

typedef __attribute__((ext_vector_type(8))) short short8v;  // 8 bf16
typedef __attribute__((ext_vector_type(4))) short short4v;  // 4 bf16
typedef __attribute__((ext_vector_type(4))) float f32x4;
typedef unsigned int u32;
typedef __attribute__((address_space(1))) const u32* gp_t;
typedef __attribute__((address_space(3))) u32* lp_t;

#define MFMA(a, b, c) __builtin_amdgcn_mfma_f32_16x16x32_bf16((a), (b), (c), 0, 0, 0)

__device__ __forceinline__ unsigned short f2bf(float f) {  // RNE fp32->bf16
  unsigned int u = __float_as_uint(f);
  u = (u + 0x7fffu + ((u >> 16) & 1u)) >> 16;
  return (unsigned short)u;
}
__device__ __forceinline__ float bf2f(unsigned short h) {
  return __uint_as_float(((unsigned int)h) << 16);
}

// ---------------- fp32 -> bf16 convert (x4 vectorized) ----------------
__global__ void k_cvt(const float* __restrict__ in, unsigned short* __restrict__ out,
                      int n4, float scale) {
  int stride = gridDim.x * blockDim.x;
  for (int i = blockIdx.x * blockDim.x + threadIdx.x; i < n4; i += stride) {
    float4 v = reinterpret_cast<const float4*>(in)[i];
    ushort4 o;
    o.x = f2bf(v.x * scale); o.y = f2bf(v.y * scale);
    o.z = f2bf(v.z * scale); o.w = f2bf(v.w * scale);
    reinterpret_cast<ushort4*>(out)[i] = o;
  }
}

// ------------- transpose+convert 1024x1024 weight: out[j][i] = in[i][j]*scale -------------
__global__ void k_cvt_t(const float* __restrict__ in, unsigned short* __restrict__ out,
                        float scale) {
  __shared__ float tile[32][33];
  int bx = blockIdx.x * 32, by = blockIdx.y * 32;
  int tx = threadIdx.x, ty = threadIdx.y;  // block (32,8)
  for (int r = ty; r < 32; r += 8)
    tile[r][tx] = in[(size_t)(by + r) * 1024 + bx + tx];
  __syncthreads();
  for (int r = ty; r < 32; r += 8)
    out[(size_t)(bx + r) * 1024 + by + tx] = f2bf(tile[tx][r] * scale);
}

// ------------- bias permute: fragment-layout gather, *LOG2E, bf16 -------------
// out[(((fb*32 + ch)*64 + lane)*16) + tt*4 + r] = bias[fb*16 + (lane&15)][ch*64 + tt*16 + (lane>>4)*4 + r]
__global__ void k_bias_perm(const float* __restrict__ in, unsigned short* __restrict__ out) {
  int t = blockIdx.x * 256 + threadIdx.x;  // 4M elems
  int e = t & 15;
  int tt = e >> 2, r = e & 3;
  int lane = (t >> 4) & 63;
  int g = lane >> 4, l15 = lane & 15;
  int ch = (t >> 10) & 31;
  int fb = t >> 15;
  float v = in[(size_t)(fb * 16 + l15) * 2048 + ch * 64 + tt * 16 + g * 4 + r];
  out[t] = f2bf(v * LOG2E);
}

// ---------------- bf16 GEMM: C[4096][1024] = A[4096][1024] * BT[1024][1024]^T ----------------
// BM=128, BN=64, BK=64; 4 waves (2m x 2n), wave tile 64x32.
// global_load_lds staging, linear LDS, both-sides XOR swizzle (chunk ^= row&7).
// mode 0: bf16 -> [b][head][s][64] ; mode 1: bf16 -> [b][head][64][s] ; mode 2: f32 row-major
__global__ __launch_bounds__(256)
void k_gemm(const unsigned short* __restrict__ A, const unsigned short* __restrict__ BT,
            void* __restrict__ dst, int mode) {
  __shared__ __align__(16) unsigned short Al[128 * 64];
  __shared__ __align__(16) unsigned short Bl[64 * 64];
  const int tid = threadIdx.x;
  const int lane = tid & 63, wid = tid >> 6;
  const int g = lane >> 4, l15 = lane & 15;
  const int wm = wid >> 1, wn = wid & 1;
  const int rowbase = blockIdx.y * 128;
  const int colbase = blockIdx.x * 64;
  const int axor = (l15 & 7) << 4;

  const f32x4 zf = {0.f, 0.f, 0.f, 0.f};
  f32x4 acc[4][2];
  for (int m = 0; m < 4; ++m)
    for (int n = 0; n < 2; ++n) acc[m][n] = zf;

  const char* Alc = (const char*)Al;
  const char* Blc = (const char*)Bl;

  for (int k0 = 0; k0 < 1024; k0 += 64) {
    // stage A: 1024 16B-chunks, 4 per thread; source col-chunk pre-swizzled
    for (int pass = 0; pass < 4; ++pass) {
      int cid = pass * 256 + tid;
      int row = cid >> 3, c = cid & 7;
      const unsigned short* src = &A[(size_t)(rowbase + row) * 1024 + k0 + ((c ^ (row & 7)) << 3)];
      __builtin_amdgcn_global_load_lds((gp_t)src, (lp_t)((char*)Al + cid * 16), 16, 0, 0);
    }
    for (int pass = 0; pass < 2; ++pass) {
      int cid = pass * 256 + tid;
      int row = cid >> 3, c = cid & 7;
      const unsigned short* src = &BT[(size_t)(colbase + row) * 1024 + k0 + ((c ^ (row & 7)) << 3)];
      __builtin_amdgcn_global_load_lds((gp_t)src, (lp_t)((char*)Bl + cid * 16), 16, 0, 0);
    }
    __syncthreads();
    for (int kk = 0; kk < 2; ++kk) {
      short8v af[4], bfr[2];
      for (int m = 0; m < 4; ++m)
        af[m] = *reinterpret_cast<const short8v*>(
            Alc + ((((wm * 64 + m * 16 + l15) << 7) + (kk << 6) + (g << 4)) ^ axor));
      for (int n = 0; n < 2; ++n)
        bfr[n] = *reinterpret_cast<const short8v*>(
            Blc + ((((wn * 32 + n * 16 + l15) << 7) + (kk << 6) + (g << 4)) ^ axor));
      for (int m = 0; m < 4; ++m)
        for (int n = 0; n < 2; ++n) acc[m][n] = MFMA(af[m], bfr[n], acc[m][n]);
    }
    __syncthreads();
  }

  for (int m = 0; m < 4; ++m) {
    for (int n = 0; n < 2; ++n) {
      for (int r = 0; r < 4; ++r) {
        int row = rowbase + wm * 64 + m * 16 + g * 4 + r;  // C/D: row=(lane>>4)*4+reg
        int col = colbase + wn * 32 + n * 16 + l15;        //      col=lane&15
        float v = acc[m][n][r];
        if (mode == 2) {
          reinterpret_cast<float*>(dst)[(size_t)row * 1024 + col] = v;
        } else {
          int b = row >> 11, s = row & 2047;
          int hd = col >> 6, h = col & 63;
          unsigned short* o = reinterpret_cast<unsigned short*>(dst);
          if (mode == 0)
            o[((size_t)(b * 16 + hd) * 2048 + s) * 64 + h] = f2bf(v);
          else
            o[((size_t)(b * 16 + hd) * 64 + h) * 2048 + s] = f2bf(v);
        }
      }
    }
  }
}

// ---------------- flash attention, transposed-S structure ----------------
// block = (f-tile of 64, one (b,head)); 4 waves, each wave owns 16 f-rows.
// S^T = MFMA(K, Q): lane holds one f-row (f = f0 + lane&15) -> softmax mostly lane-local.
__global__ __launch_bounds__(256, 4)
void k_attn(const unsigned short* __restrict__ qw,    // [B*N][F][64] (q * scale * log2e folded)
            const unsigned short* __restrict__ kw,    // [B*N][T][64]
            const unsigned short* __restrict__ vtw,   // [B*N][64][T]
            const unsigned short* __restrict__ biasp, // permuted bf16 (* log2e)
            unsigned short* __restrict__ attnb) {     // [B][F][N*64] bf16
  __shared__ __align__(16) unsigned short Kl[64 * LDT];
  __shared__ __align__(16) unsigned short Vl[64 * LDT];
  __shared__ __align__(16) unsigned short Pl[4][16 * LDT];

  const int tid = threadIdx.x;
  const int lane = tid & 63, wid = tid >> 6;
  const int g = lane >> 4, l15 = lane & 15;

  const int bid = blockIdx.x;  // bid = ftile*32 + bn (bias-slab L2 locality)
  const int ft = bid >> 5;
  const int bn = bid & 31;
  const int b = bn >> 4, n = bn & 15;

  const size_t hoff = (size_t)bn * 2048 * 64;
  const unsigned short* qp = qw + hoff;
  const unsigned short* kp = kw + hoff;
  const unsigned short* vp = vtw + hoff;

  const int f0 = ft * 64 + wid * 16;  // this wave's 16 f-rows
  const int fb = ft * 4 + wid;        // bias row-block index 0..127

  // Q as B-fragment (col = f, k = h): lane reads Q[f0+l15][kk*32 + g*8 ..]
  short8v aq[2];
  for (int kk = 0; kk < 2; ++kk)
    aq[kk] = *reinterpret_cast<const short8v*>(&qp[(size_t)(f0 + l15) * 64 + kk * 32 + g * 8]);

  const f32x4 zf = {0.f, 0.f, 0.f, 0.f};
  f32x4 o[4];
  for (int ht = 0; ht < 4; ++ht) o[ht] = zf;
  float ms = -1e30f, ls = 0.f;

  // staging geometry: chunk = 4096 bf16; thread loads 2x short8v for K, 2 for V
  const int e0 = tid * 8, e1 = tid * 8 + 2048;
  short8v kr0, kr1, vr0, vr1;

  // prologue: stage chunk 0
  kr0 = *reinterpret_cast<const short8v*>(&kp[e0]);
  kr1 = *reinterpret_cast<const short8v*>(&kp[e1]);
  vr0 = *reinterpret_cast<const short8v*>(&vp[(e0 >> 6) * 2048 + (e0 & 63)]);
  vr1 = *reinterpret_cast<const short8v*>(&vp[(e1 >> 6) * 2048 + (e1 & 63)]);
  *reinterpret_cast<short8v*>(&Kl[(e0 >> 6) * LDT + (e0 & 63)]) = kr0;
  *reinterpret_cast<short8v*>(&Kl[(e1 >> 6) * LDT + (e1 & 63)]) = kr1;
  *reinterpret_cast<short8v*>(&Vl[(e0 >> 6) * LDT + (e0 & 63)]) = vr0;
  *reinterpret_cast<short8v*>(&Vl[(e1 >> 6) * LDT + (e1 & 63)]) = vr1;
  __syncthreads();

  for (int ci = 0; ci < 32; ++ci) {
    const int tn = ((ci + 1) & 31) * 64;  // next chunk (wraps; last iter redundant)

    // T14: issue next-chunk global loads before compute
    kr0 = *reinterpret_cast<const short8v*>(&kp[tn * 64 + e0]);
    kr1 = *reinterpret_cast<const short8v*>(&kp[tn * 64 + e1]);
    vr0 = *reinterpret_cast<const short8v*>(&vp[(e0 >> 6) * 2048 + tn + (e0 & 63)]);
    vr1 = *reinterpret_cast<const short8v*>(&vp[(e1 >> 6) * 2048 + tn + (e1 & 63)]);

    // bias for this chunk: 16 contiguous bf16 per lane
    const short8v* bp = reinterpret_cast<const short8v*>(
        &biasp[(((size_t)fb * 32 + ci) * 64 + lane) * 16]);
    short8v bb0 = bp[0], bb1 = bp[1];

    // S^T = K * Q : rows t (= tt*16 + g*4 + r), col f (= f0 + l15)
    f32x4 st[4];
    for (int tt = 0; tt < 4; ++tt) {
      short8v kb0 = *reinterpret_cast<const short8v*>(&Kl[(tt * 16 + l15) * LDT + g * 8]);
      short8v kb1 = *reinterpret_cast<const short8v*>(&Kl[(tt * 16 + l15) * LDT + 32 + g * 8]);
      f32x4 t0 = MFMA(kb0, aq[0], zf);
      st[tt] = MFMA(kb1, aq[1], t0);
    }
    for (int tt = 0; tt < 4; ++tt)
      for (int r = 0; r < 4; ++r)
        st[tt][r] += bf2f((unsigned short)((tt < 2) ? bb0[tt * 4 + r] : bb1[(tt - 2) * 4 + r]));

    // lane-local tile max over 16, then reduce across the 4 g-groups
    float tm = st[0][0];
    for (int tt = 0; tt < 4; ++tt)
      for (int r = 0; r < 4; ++r) tm = fmaxf(tm, st[tt][r]);
    tm = fmaxf(tm, __shfl_xor(tm, 16));
    tm = fmaxf(tm, __shfl_xor(tm, 32));

    // defer-max (T13): rescale only if some row grew past THR=8 (exp2 domain)
    if (__any(tm > ms + 8.0f)) {
      float mn = fmaxf(ms, tm);
      float sc = __builtin_amdgcn_exp2f(ms - mn);
      ms = mn;
      ls *= sc;
      float scr[4];
      for (int r = 0; r < 4; ++r) scr[r] = __shfl(sc, ((lane >> 4) << 2) + r, 16);
      for (int ht = 0; ht < 4; ++ht)
        for (int r = 0; r < 4; ++r) o[ht][r] *= scr[r];
    }

    // P = exp2(s - m), row-sum, pack to LDS as b64 (4 consecutive t-cols per write)
    float rs = 0.f;
    for (int tt = 0; tt < 4; ++tt) {
      short4v h;
      for (int r = 0; r < 4; ++r) {
        float p = __builtin_amdgcn_exp2f(st[tt][r] - ms);
        rs += p;
        h[r] = f2bf(p);
      }
      *reinterpret_cast<short4v*>(&Pl[wid][l15 * LDT + tt * 16 + g * 4]) = h;
    }
    rs += __shfl_xor(rs, 16);
    rs += __shfl_xor(rs, 32);
    ls += rs;

    // O += P * V : A = P rows f, B = V^T cols h
    for (int c = 0; c < 2; ++c) {
      short8v pa = *reinterpret_cast<const short8v*>(&Pl[wid][l15 * LDT + c * 32 + g * 8]);
      for (int ht = 0; ht < 4; ++ht) {
        short8v vb = *reinterpret_cast<const short8v*>(&Vl[(ht * 16 + l15) * LDT + c * 32 + g * 8]);
        o[ht] = MFMA(pa, vb, o[ht]);
      }
    }

    __syncthreads();  // all waves done reading chunk ci
    *reinterpret_cast<short8v*>(&Kl[(e0 >> 6) * LDT + (e0 & 63)]) = kr0;
    *reinterpret_cast<short8v*>(&Kl[(e1 >> 6) * LDT + (e1 & 63)]) = kr1;
    *reinterpret_cast<short8v*>(&Vl[(e0 >> 6) * LDT + (e0 & 63)]) = vr0;
    *reinterpret_cast<short8v*>(&Vl[(e1 >> 6) * LDT + (e1 & 63)]) = vr1;
    __syncthreads();  // chunk ci+1 visible
  }

  float inv = 1.f / ls;  // per f-row (f = f0 + l15), uniform across g
  float invr[4];
  for (int r = 0; r < 4; ++r) invr[r] = __shfl(inv, ((lane >> 4) << 2) + r, 16);
  for (int ht = 0; ht < 4; ++ht)
    for (int r = 0; r < 4; ++r) {
      int f = f0 + g * 4 + r;
      attnb[((size_t)b * 2048 + f) * 1024 + n * 64 + ht * 16 + l15] =
          f2bf(o[ht][r] * invr[r]);
    }
}

extern "C" void kernel_launch(void* const* d_in, const int* in_sizes, int n_in,
                              void* d_out, int out_size, void* d_ws, size_t ws_size,
                              hipStream_t stream) {
  const float* query  = (const float*)d_in[0];
  const float* source = (const float*)d_in[1];
  const float* bias   = (const float*)d_in[2];
  const float* wq     = (const float*)d_in[3];
  const float* wk     = (const float*)d_in[4];
  const float* wv     = (const float*)d_in[5];
  const float* wo     = (const float*)d_in[6];

  char* ws = (char*)d_ws;  // 64 MB total
  unsigned short* qin_b  = (unsigned short*)(ws + 0);         // [4096][1024] bf16
  unsigned short* src_b  = (unsigned short*)(ws + 8388608);   // [4096][1024]
  unsigned short* wqT    = (unsigned short*)(ws + 16777216);  // [1024][1024] (*0.125*log2e)
  unsigned short* wkT    = (unsigned short*)(ws + 18874368);
  unsigned short* wvT    = (unsigned short*)(ws + 20971520);
  unsigned short* woT    = (unsigned short*)(ws + 23068672);
  unsigned short* bias_p = (unsigned short*)(ws + 25165824);  // permuted bf16 (*log2e)
  unsigned short* q_ws   = (unsigned short*)(ws + 33554432);  // [32][2048][64]
  unsigned short* k_ws   = (unsigned short*)(ws + 41943040);  // [32][2048][64]
  unsigned short* vT_ws  = (unsigned short*)(ws + 50331648);  // [32][64][2048]
  unsigned short* attn_b = (unsigned short*)(ws + 58720256);  // [4096][1024]

  k_cvt<<<2048, 256, 0, stream>>>(query,  qin_b, 1048576, 1.0f);
  k_cvt<<<2048, 256, 0, stream>>>(source, src_b, 1048576, 1.0f);
  k_bias_perm<<<16384, 256, 0, stream>>>(bias, bias_p);
  dim3 tb(32, 8);
  k_cvt_t<<<dim3(32, 32), tb, 0, stream>>>(wq, wqT, 0.125f * LOG2E);  // depth^-0.5 * log2e
  k_cvt_t<<<dim3(32, 32), tb, 0, stream>>>(wk, wkT, 1.0f);
  k_cvt_t<<<dim3(32, 32), tb, 0, stream>>>(wv, wvT, 1.0f);
  k_cvt_t<<<dim3(32, 32), tb, 0, stream>>>(wo, woT, 1.0f);

  k_gemm<<<dim3(16, 32), 256, 0, stream>>>(qin_b, wqT, q_ws, 0);
  k_gemm<<<dim3(16, 32), 256, 0, stream>>>(src_b, wkT, k_ws, 0);
  k_gemm<<<dim3(16, 32), 256, 0, stream>>>(src_b, wvT, vT_ws, 1);
  k_attn<<<1024, 256, 0, stream>>>(q_ws, k_ws, vT_ws, bias_p, attn_b);
  k_gemm<<<dim3(16, 32), 256, 0, stream>>>(attn_b, woT, d_out, 2);
}

// Round 3
// 166.027 us; speedup vs baseline: 1.8646x; 1.1452x over previous
//
#include <hip/hip_runtime.h>

// Shapes: B=2, F=T=2048, HIDDEN=1024, HEADS=16, DEPTH=64
#define LOG2E 1.44269504f

typedef __attribute__((ext_vector_type(8))) short short8v;  // 8 bf16
typedef __attribute__((ext_vector_type(4))) float f32x4;
typedef unsigned int u32;
typedef __attribute__((address_space(1))) const u32* gp_t;
typedef __attribute__((address_space(3))) u32* lp_t;

#define MFMA(a, b, c) __builtin_amdgcn_mfma_f32_16x16x32_bf16((a), (b), (c), 0, 0, 0)

__device__ __forceinline__ unsigned short f2bf(float f) {  // RNE fp32->bf16
  unsigned int u = __float_as_uint(f);
  u = (u + 0x7fffu + ((u >> 16) & 1u)) >> 16;
  return (unsigned short)u;
}
__device__ __forceinline__ float bf2f(unsigned short h) {
  return __uint_as_float(((unsigned int)h) << 16);
}
__device__ __forceinline__ u32 cvtpk(float lo, float hi) {  // HW RNE pack (T12)
  u32 r;
  asm("v_cvt_pk_bf16_f32 %0, %1, %2" : "=v"(r) : "v"(lo), "v"(hi));
  return r;
}

// ---------------- fp32 -> bf16 convert (x4 vectorized) ----------------
__global__ void k_cvt(const float* __restrict__ in, unsigned short* __restrict__ out,
                      int n4, float scale) {
  int stride = gridDim.x * blockDim.x;
  for (int i = blockIdx.x * blockDim.x + threadIdx.x; i < n4; i += stride) {
    float4 v = reinterpret_cast<const float4*>(in)[i];
    ushort4 o;
    o.x = f2bf(v.x * scale); o.y = f2bf(v.y * scale);
    o.z = f2bf(v.z * scale); o.w = f2bf(v.w * scale);
    reinterpret_cast<ushort4*>(out)[i] = o;
  }
}

// ------------- transpose+convert 1024x1024 weight: out[j][i] = in[i][j]*scale -------------
__global__ void k_cvt_t(const float* __restrict__ in, unsigned short* __restrict__ out,
                        float scale) {
  __shared__ float tile[32][33];
  int bx = blockIdx.x * 32, by = blockIdx.y * 32;
  int tx = threadIdx.x, ty = threadIdx.y;  // block (32,8)
  for (int r = ty; r < 32; r += 8)
    tile[r][tx] = in[(size_t)(by + r) * 1024 + bx + tx];
  __syncthreads();
  for (int r = ty; r < 32; r += 8)
    out[(size_t)(bx + r) * 1024 + by + tx] = f2bf(tile[tx][r] * scale);
}

// ------------- bias permute to MFMA C-fragment layout, *LOG2E, bf16 (coalesced reads) ---
// target: out[((fb*32+ch)*64 + g*16+l15)*16 + tt*4 + r] = bias[fb*16+l15][ch*64+tt*16+g*4+r]*LOG2E
__global__ void k_bias_perm(const float* __restrict__ in, unsigned short* __restrict__ out) {
  int fb = blockIdx.x >> 5, ch = blockIdx.x & 31;  // grid 4096
  int tid = threadIdx.x;
  int row = tid >> 4;  // = l15
  int q = tid & 15;    // col = q*4 + j
  float4 v = *reinterpret_cast<const float4*>(
      &in[(size_t)(fb * 16 + row) * 2048 + ch * 64 + q * 4]);
  int tt = q >> 2, g = q & 3;
  unsigned short* ob = out + (((size_t)(fb * 32 + ch) * 64) << 4);
  ushort4 o;
  o.x = f2bf(v.x * LOG2E); o.y = f2bf(v.y * LOG2E);
  o.z = f2bf(v.z * LOG2E); o.w = f2bf(v.w * LOG2E);
  *reinterpret_cast<ushort4*>(&ob[(g * 16 + row) * 16 + tt * 4]) = o;
}

// ---------------- bf16 GEMM: C[4096][Ncols] = A[4096][1024] * BT[Ncols][1024]^T ----------
// BM=BN=BK=64, 4 waves (2x2), wave tile 32x32. gload_lds staging, XOR-swizzled LDS,
// double-buffered, 1 barrier per K-step.
// mode 0: bf16 -> [b][head][s][64] ; mode 2: f32 row-major [4096][1024]
// mode 3: fused KV: col<1024 -> K layout (dst), col>=1024 -> V^T layout (dst2)
__global__ __launch_bounds__(256, 4)
void k_gemm(const unsigned short* __restrict__ A, const unsigned short* __restrict__ BT,
            void* dst, void* dst2, int mode) {
  __shared__ __align__(16) unsigned short Al[2][4096];
  __shared__ __align__(16) unsigned short Bl[2][4096];
  const int tid = threadIdx.x;
  const int lane = tid & 63, wid = tid >> 6;
  const int g = lane >> 4, l15 = lane & 15, l7 = l15 & 7;
  const int wm = wid >> 1, wn = wid & 1;
  const int rowbase = blockIdx.y * 64, colbase = blockIdx.x * 64;
  const int xgl = (g ^ l7) << 4;

  // staging sources (pre-swizzled): chunk j -> row j>>3; phys col-chunk j&7 holds logical (j&7)^(row&7)
  const int jr = tid >> 3;
  const int sc = ((tid & 7) ^ (jr & 7)) << 3;
  const unsigned short* As0 = A + (size_t)(rowbase + jr) * 1024 + sc;
  const unsigned short* As1 = A + (size_t)(rowbase + jr + 32) * 1024 + sc;
  const unsigned short* Bs0 = BT + (size_t)(colbase + jr) * 1024 + sc;
  const unsigned short* Bs1 = BT + (size_t)(colbase + jr + 32) * 1024 + sc;

  const f32x4 zf = {0.f, 0.f, 0.f, 0.f};
  f32x4 acc[2][2];
  acc[0][0] = zf; acc[0][1] = zf; acc[1][0] = zf; acc[1][1] = zf;

  auto stage = [&](char* Ad, char* Bd, int step) {
    int ko = step << 6;  // 64 elems per K-step
    __builtin_amdgcn_global_load_lds((gp_t)(As0 + ko), (lp_t)(Ad + tid * 16), 16, 0, 0);
    __builtin_amdgcn_global_load_lds((gp_t)(As1 + ko), (lp_t)(Ad + 4096 + tid * 16), 16, 0, 0);
    __builtin_amdgcn_global_load_lds((gp_t)(Bs0 + ko), (lp_t)(Bd + tid * 16), 16, 0, 0);
    __builtin_amdgcn_global_load_lds((gp_t)(Bs1 + ko), (lp_t)(Bd + 4096 + tid * 16), 16, 0, 0);
  };
  auto compute = [&](const unsigned short* Ab, const unsigned short* Bb) {
    const char* Ac = (const char*)Ab; const char* Bc = (const char*)Bb;
    __builtin_amdgcn_s_setprio(1);
#pragma unroll
    for (int kk = 0; kk < 2; ++kk) {
      short8v af[2], bfr[2];
#pragma unroll
      for (int mf = 0; mf < 2; ++mf)
        af[mf] = *reinterpret_cast<const short8v*>(
            Ac + ((wm * 32 + mf * 16 + l15) << 7) + (xgl ^ (kk << 6)));
#pragma unroll
      for (int nf = 0; nf < 2; ++nf)
        bfr[nf] = *reinterpret_cast<const short8v*>(
            Bc + ((wn * 32 + nf * 16 + l15) << 7) + (xgl ^ (kk << 6)));
#pragma unroll
      for (int mf = 0; mf < 2; ++mf)
#pragma unroll
        for (int nf = 0; nf < 2; ++nf) acc[mf][nf] = MFMA(af[mf], bfr[nf], acc[mf][nf]);
    }
    __builtin_amdgcn_s_setprio(0);
  };

  char* A0d = (char*)&Al[0][0]; char* A1d = (char*)&Al[1][0];
  char* B0d = (char*)&Bl[0][0]; char* B1d = (char*)&Bl[1][0];

  stage(A0d, B0d, 0);
  __syncthreads();
#pragma unroll 1
  for (int s = 0; s < 16; s += 2) {
    stage(A1d, B1d, (s + 1) & 15);
    compute(Al[0], Bl[0]);
    __syncthreads();
    stage(A0d, B0d, (s + 2) & 15);
    compute(Al[1], Bl[1]);
    __syncthreads();
  }

#pragma unroll
  for (int mf = 0; mf < 2; ++mf)
#pragma unroll
    for (int nf = 0; nf < 2; ++nf)
#pragma unroll
      for (int r = 0; r < 4; ++r) {
        int row = rowbase + wm * 32 + mf * 16 + g * 4 + r;  // C/D: row=(lane>>4)*4+reg
        int col = colbase + wn * 32 + nf * 16 + l15;        //      col=lane&15
        float v = acc[mf][nf][r];
        if (mode == 2) {
          reinterpret_cast<float*>(dst)[(size_t)row * 1024 + col] = v;
        } else {
          int b = row >> 11, s = row & 2047;
          if (mode == 0 || col < 1024) {
            int hd = col >> 6, h = col & 63;
            reinterpret_cast<unsigned short*>(dst)[((size_t)(b * 16 + hd) * 2048 + s) * 64 + h] =
                f2bf(v);
          } else {
            int c2 = col - 1024;
            int hd = c2 >> 6, h = c2 & 63;
            reinterpret_cast<unsigned short*>(dst2)[((size_t)(b * 16 + hd) * 64 + h) * 2048 + s] =
                f2bf(v);
          }
        }
      }
}

// ---------------- flash attention, transposed-S, dbuf + gload_lds + swizzle ----------------
// block = (f-tile 64, one (b,head)); 4 waves x 16 f-rows. 1 barrier/chunk.
__global__ __launch_bounds__(256, 4)
void k_attn(const unsigned short* __restrict__ qw,    // [B*N][F][64] (* scale * log2e)
            const unsigned short* __restrict__ kw,    // [B*N][T][64]
            const unsigned short* __restrict__ vtw,   // [B*N][64][T]
            const unsigned short* __restrict__ biasp, // C-frag-layout bf16 (* log2e)
            unsigned short* __restrict__ attnb) {     // [B][F][N*64] bf16
  __shared__ __align__(16) unsigned short Kl[2][4096];
  __shared__ __align__(16) unsigned short Vl[2][4096];
  __shared__ __align__(16) unsigned short Pl[4][1024];

  const int tid = threadIdx.x;
  const int lane = tid & 63, wid = tid >> 6;
  const int g = lane >> 4, l15 = lane & 15, l7 = l15 & 7;
  const int xgl = (g ^ l7) << 4;

  const int bid = blockIdx.x;  // ft-major: 32 consecutive blocks share a bias slab
  const int ft = bid >> 5, bn = bid & 31;
  const int b = bn >> 4, n = bn & 15;

  const size_t hoff = (size_t)bn * (2048 * 64);
  const unsigned short* qp = qw + hoff;
  const unsigned short* kp = kw + hoff;
  const unsigned short* vp = vtw + hoff;

  const int f0 = ft * 64 + wid * 16;
  const int fb = ft * 4 + wid;

  // staging sources (pre-swizzled)
  const int jr = tid >> 3;
  const int sc = ((tid & 7) ^ (jr & 7)) << 3;
  const unsigned short* Ks0 = kp + jr * 64 + sc;
  const unsigned short* Ks1 = kp + (jr + 32) * 64 + sc;
  const unsigned short* Vs0 = vp + jr * 2048 + sc;
  const unsigned short* Vs1 = vp + (jr + 32) * 2048 + sc;
  char* K0d = (char*)&Kl[0][0]; char* K1d = (char*)&Kl[1][0];
  char* V0d = (char*)&Vl[0][0]; char* V1d = (char*)&Vl[1][0];

  auto stage = [&](char* Kd, char* Vd, int ci) {
    int ko = ci << 12, vo = ci << 6;
    __builtin_amdgcn_global_load_lds((gp_t)(Ks0 + ko), (lp_t)(Kd + tid * 16), 16, 0, 0);
    __builtin_amdgcn_global_load_lds((gp_t)(Ks1 + ko), (lp_t)(Kd + 4096 + tid * 16), 16, 0, 0);
    __builtin_amdgcn_global_load_lds((gp_t)(Vs0 + vo), (lp_t)(Vd + tid * 16), 16, 0, 0);
    __builtin_amdgcn_global_load_lds((gp_t)(Vs1 + vo), (lp_t)(Vd + 4096 + tid * 16), 16, 0, 0);
  };

  // Q as B-fragment (col = f = f0+l15)
  short8v aq0 = *reinterpret_cast<const short8v*>(&qp[(size_t)(f0 + l15) * 64 + g * 8]);
  short8v aq1 = *reinterpret_cast<const short8v*>(&qp[(size_t)(f0 + l15) * 64 + 32 + g * 8]);

  const unsigned short* bias_lane = biasp + (size_t)fb * 32768 + lane * 16;

  const f32x4 zf = {0.f, 0.f, 0.f, 0.f};
  f32x4 o[4];
  o[0] = zf; o[1] = zf; o[2] = zf; o[3] = zf;
  float ms = -1e30f, ls = 0.f;
  char* Pbl = (char*)&Pl[wid][0] + l15 * 128;

  auto bload = [&](int ci, short8v& b0, short8v& b1) {
    const short8v* p = reinterpret_cast<const short8v*>(bias_lane + ci * 1024);
    b0 = p[0]; b1 = p[1];
  };

  auto compute = [&](const unsigned short* Kb, const unsigned short* Vb,
                     short8v bb0, short8v bb1) {
    const char* Kc = (const char*)Kb; const char* Vc = (const char*)Vb;
    f32x4 st[4];
    __builtin_amdgcn_s_setprio(1);
#pragma unroll
    for (int tt = 0; tt < 4; ++tt) {
      f32x4 bc;
#pragma unroll
      for (int r = 0; r < 4; ++r) {
        short h = (tt < 2) ? bb0[(tt & 1) * 4 + r] : bb1[(tt & 1) * 4 + r];
        bc[r] = bf2f((unsigned short)h);
      }
      short8v kb0 = *reinterpret_cast<const short8v*>(Kc + ((tt * 16 + l15) << 7) + xgl);
      short8v kb1 = *reinterpret_cast<const short8v*>(Kc + ((tt * 16 + l15) << 7) + (xgl ^ 64));
      st[tt] = MFMA(kb1, aq1, MFMA(kb0, aq0, bc));
    }
    __builtin_amdgcn_s_setprio(0);

    float t0 = fmaxf(fmaxf(st[0][0], st[0][1]), fmaxf(st[0][2], st[0][3]));
    float t1 = fmaxf(fmaxf(st[1][0], st[1][1]), fmaxf(st[1][2], st[1][3]));
    float t2 = fmaxf(fmaxf(st[2][0], st[2][1]), fmaxf(st[2][2], st[2][3]));
    float t3 = fmaxf(fmaxf(st[3][0], st[3][1]), fmaxf(st[3][2], st[3][3]));
    float tm = fmaxf(fmaxf(t0, t1), fmaxf(t2, t3));
    tm = fmaxf(tm, __shfl_xor(tm, 16));
    tm = fmaxf(tm, __shfl_xor(tm, 32));

    if (__any(tm > ms + 8.0f)) {  // defer-max (T13), exp2 domain
      float mn = fmaxf(ms, tm);
      float sca = __builtin_amdgcn_exp2f(ms - mn);
      ms = mn; ls *= sca;
      float s0 = __shfl(sca, g * 4 + 0, 16);
      float s1 = __shfl(sca, g * 4 + 1, 16);
      float s2 = __shfl(sca, g * 4 + 2, 16);
      float s3 = __shfl(sca, g * 4 + 3, 16);
#pragma unroll
      for (int ht = 0; ht < 4; ++ht) {
        o[ht][0] *= s0; o[ht][1] *= s1; o[ht][2] *= s2; o[ht][3] *= s3;
      }
    }

    float rs = 0.f;
#pragma unroll
    for (int tt = 0; tt < 4; ++tt) {
      float p0 = __builtin_amdgcn_exp2f(st[tt][0] - ms);
      float p1 = __builtin_amdgcn_exp2f(st[tt][1] - ms);
      float p2 = __builtin_amdgcn_exp2f(st[tt][2] - ms);
      float p3 = __builtin_amdgcn_exp2f(st[tt][3] - ms);
      rs += (p0 + p1) + (p2 + p3);
      uint2 w;
      w.x = cvtpk(p0, p1);
      w.y = cvtpk(p2, p3);
      *reinterpret_cast<uint2*>(Pbl + ((tt * 32 + g * 8) ^ (l7 * 16))) = w;
    }
    rs += __shfl_xor(rs, 16);
    rs += __shfl_xor(rs, 32);
    ls += rs;

    __builtin_amdgcn_s_setprio(1);
#pragma unroll
    for (int c = 0; c < 2; ++c) {
      short8v pa = *reinterpret_cast<const short8v*>(Pbl + ((c << 6) ^ xgl));
#pragma unroll
      for (int ht = 0; ht < 4; ++ht) {
        short8v vb = *reinterpret_cast<const short8v*>(
            Vc + ((ht * 16 + l15) << 7) + (xgl ^ (c << 6)));
        o[ht] = MFMA(pa, vb, o[ht]);
      }
    }
    __builtin_amdgcn_s_setprio(0);
  };

  short8v cb0, cb1, nb0, nb1;
  stage(K0d, V0d, 0);
  bload(0, cb0, cb1);
  __syncthreads();
#pragma unroll 1
  for (int ci = 0; ci < 32; ci += 2) {
    stage(K1d, V1d, (ci + 1) & 31);
    bload((ci + 1) & 31, nb0, nb1);
    compute(Kl[0], Vl[0], cb0, cb1);
    cb0 = nb0; cb1 = nb1;
    __syncthreads();
    stage(K0d, V0d, (ci + 2) & 31);
    bload((ci + 2) & 31, nb0, nb1);
    compute(Kl[1], Vl[1], cb0, cb1);
    cb0 = nb0; cb1 = nb1;
    __syncthreads();
  }

  float inv = 1.f / ls;
  float i0 = __shfl(inv, g * 4 + 0, 16);
  float i1 = __shfl(inv, g * 4 + 1, 16);
  float i2 = __shfl(inv, g * 4 + 2, 16);
  float i3 = __shfl(inv, g * 4 + 3, 16);
#pragma unroll
  for (int ht = 0; ht < 4; ++ht) {
    unsigned short* ob = &attnb[((size_t)b * 2048 + f0 + g * 4) * 1024 + n * 64 + ht * 16 + l15];
    ob[0] = f2bf(o[ht][0] * i0);
    ob[1024] = f2bf(o[ht][1] * i1);
    ob[2048] = f2bf(o[ht][2] * i2);
    ob[3072] = f2bf(o[ht][3] * i3);
  }
}

extern "C" void kernel_launch(void* const* d_in, const int* in_sizes, int n_in,
                              void* d_out, int out_size, void* d_ws, size_t ws_size,
                              hipStream_t stream) {
  const float* query  = (const float*)d_in[0];
  const float* source = (const float*)d_in[1];
  const float* bias   = (const float*)d_in[2];
  const float* wq     = (const float*)d_in[3];
  const float* wk     = (const float*)d_in[4];
  const float* wv     = (const float*)d_in[5];
  const float* wo     = (const float*)d_in[6];

  char* ws = (char*)d_ws;  // 64 MB
  unsigned short* qin_b  = (unsigned short*)(ws + 0);         // [4096][1024] bf16
  unsigned short* src_b  = (unsigned short*)(ws + 8388608);   // [4096][1024]
  unsigned short* wqT    = (unsigned short*)(ws + 16777216);  // [1024][1024] (*0.125*log2e)
  unsigned short* wkvT   = (unsigned short*)(ws + 18874368);  // [2048][1024] fused K|V
  unsigned short* woT    = (unsigned short*)(ws + 23068672);  // [1024][1024]
  unsigned short* bias_p = (unsigned short*)(ws + 25165824);  // C-frag bf16 (*log2e)
  unsigned short* q_ws   = (unsigned short*)(ws + 33554432);  // [32][2048][64]
  unsigned short* k_ws   = (unsigned short*)(ws + 41943040);  // [32][2048][64]
  unsigned short* vT_ws  = (unsigned short*)(ws + 50331648);  // [32][64][2048]
  unsigned short* attn_b = (unsigned short*)(ws + 58720256);  // [4096][1024]

  k_cvt<<<2048, 256, 0, stream>>>(query,  qin_b, 1048576, 1.0f);
  k_cvt<<<2048, 256, 0, stream>>>(source, src_b, 1048576, 1.0f);
  k_bias_perm<<<4096, 256, 0, stream>>>(bias, bias_p);
  dim3 tb(32, 8);
  k_cvt_t<<<dim3(32, 32), tb, 0, stream>>>(wq, wqT, 0.125f * LOG2E);
  k_cvt_t<<<dim3(32, 32), tb, 0, stream>>>(wk, wkvT, 1.0f);
  k_cvt_t<<<dim3(32, 32), tb, 0, stream>>>(wv, wkvT + 1048576, 1.0f);
  k_cvt_t<<<dim3(32, 32), tb, 0, stream>>>(wo, woT, 1.0f);

  k_gemm<<<dim3(16, 64), 256, 0, stream>>>(qin_b, wqT, q_ws, q_ws, 0);
  k_gemm<<<dim3(32, 64), 256, 0, stream>>>(src_b, wkvT, k_ws, vT_ws, 3);
  k_attn<<<1024, 256, 0, stream>>>(q_ws, k_ws, vT_ws, bias_p, attn_b);
  k_gemm<<<dim3(16, 64), 256, 0, stream>>>(attn_b, woT, d_out, d_out, 2);
}